// Round 3
// baseline (3263.050 us; speedup 1.0000x reference)
//
#include <hip/hip_runtime.h>
#include <hip/hip_bf16.h>
#include <stdint.h>

// SAGE (GraphSAGE, LSTM aggregator). Inputs/outputs are FLOAT32 per the
// reference (jnp.float32); comparison is done at bf16 granularity, which
// licenses bf16 MFMA internally.
// N=30000 nodes, DMAX=16 neighbors, dims 128 -> 256 -> 64.
// Structure: one WG per 32-node tile; LSTM recurrence fused in-kernel.
//   - weights pre-converted f32->bf16 once per call into g_wbuf (prep kernel)
//   - c state in registers (MFMA D-layout: i,f,g,o for a (node,unit) pair in
//     the same lane -> pointwise LSTM update register-local)
//   - h state round-trips LDS (bf16) each step (A-operand of h@Whh^T)
//   - gathered x rows: f32 loads, converted to bf16 while staging to LDS
//   - fc_self/fc_neigh + bias (+relu layer 1) fused epilogue
// R2->R3: dtype flip (bf16 reads of f32 data explain the NaNs: random f32
// low-halves decode as bf16 NaN/Inf ~0.8% of the time).
// Verified layouts (learn_hip m89/m91): A[m=lane&15][k=q*8+j],
// D[row=q*4+r][col=lane&15].

#define NN 30000
#define DMAXX 16

typedef __bf16 bf16_t;
typedef __bf16 bf16x8 __attribute__((ext_vector_type(8)));
typedef float f32x4 __attribute__((ext_vector_type(4)));

// inter-layer activations h1 [30000, 256] bf16 (fully rewritten every call)
__device__ __align__(16) bf16_t g_hbuf[(size_t)NN * 256];
// bf16 copies of the 8 weight matrices, concatenated (753,664 elems)
__device__ __align__(16) bf16_t g_wbuf[753664];

// segment offsets (elements) into g_wbuf
#define OFF_WIH1 0
#define OFF_WHH1 65536
#define OFF_WSELF1 131072
#define OFF_WNEIGH1 163840
#define OFF_WIH2 196608
#define OFF_WHH2 458752
#define OFF_WSELF2 720896
#define OFF_WNEIGH2 737280
#define W_TOTAL 753664

__global__ __launch_bounds__(256)
void cvt_weights(const float* __restrict__ s0, const float* __restrict__ s1,
                 const float* __restrict__ s2, const float* __restrict__ s3,
                 const float* __restrict__ s4, const float* __restrict__ s5,
                 const float* __restrict__ s6, const float* __restrict__ s7)
{
    int i = (blockIdx.x * 256 + threadIdx.x) * 4;   // element index, quads
    if (i >= W_TOTAL) return;
    const float* src; int off;
    if      (i < OFF_WHH1)   { src = s0; off = OFF_WIH1; }
    else if (i < OFF_WSELF1) { src = s1; off = OFF_WHH1; }
    else if (i < OFF_WNEIGH1){ src = s2; off = OFF_WSELF1; }
    else if (i < OFF_WIH2)   { src = s3; off = OFF_WNEIGH1; }
    else if (i < OFF_WHH2)   { src = s4; off = OFF_WIH2; }
    else if (i < OFF_WSELF2) { src = s5; off = OFF_WHH2; }
    else if (i < OFF_WNEIGH2){ src = s6; off = OFF_WSELF2; }
    else                     { src = s7; off = OFF_WNEIGH2; }
    float4 v = *reinterpret_cast<const float4*>(src + (i - off));
    bf16_t o[4] __attribute__((aligned(8)));
    o[0] = (bf16_t)v.x; o[1] = (bf16_t)v.y; o[2] = (bf16_t)v.z; o[3] = (bf16_t)v.w;
    *reinterpret_cast<uint2*>(&g_wbuf[i]) = *reinterpret_cast<const uint2*>(o);
}

__device__ __forceinline__ float fsig(float x) { return 1.0f / (1.0f + __expf(-x)); }
__device__ __forceinline__ float ftanh(float x) { return 1.0f - 2.0f / (__expf(2.0f * x) + 1.0f); }

template<int F, int OUTF, int NW, bool RELU, bool XF32, typename OutT>
__global__ __launch_bounds__(NW * 64)
void sage_layer(const void* __restrict__ xsrc_v,
                const int* __restrict__ nbr_idx,
                const int* __restrict__ deg,
                const bf16_t* __restrict__ Wih, const bf16_t* __restrict__ Whh,
                const float* __restrict__ bih, const float* __restrict__ bhh,
                const bf16_t* __restrict__ Wself, const bf16_t* __restrict__ Wneigh,
                const float* __restrict__ bout,
                OutT* __restrict__ outp)
{
    constexpr int M = 32;            // nodes per WG
    constexpr int LDA = F + 8;       // LDS row pad (+16B) to break bank aliasing
    constexpr int KK = F / 32;       // k-chunks of 32 per MFMA
    constexpr int NT = NW * 64;
    constexpr int TPR = NT / M;      // staging threads per row (16 elems each)
    static_assert(F / NW == 32, "each wave owns 32 hidden columns");
    static_assert(F / TPR == 16, "16 elems per staging thread");

    const int tid = threadIdx.x;
    const int wave = tid >> 6;
    const int lane = tid & 63;
    const int q = lane >> 4;
    const int m16 = lane & 15;
    const int node0 = blockIdx.x * M;

    __shared__ __align__(16) bf16_t s_x[M * LDA];
    __shared__ __align__(16) bf16_t s_h[M * LDA];
    __shared__ int s_idx[M * DMAXX];
    __shared__ int s_deg[M];

    for (int i = tid; i < M * DMAXX; i += NT) {
        int m = i >> 4;
        int node = node0 + m; if (node >= NN) node = NN - 1;
        int v = nbr_idx[node * DMAXX + (i & 15)];
        if (v < 0) v = 0; if (v >= NN) v = NN - 1;   // defensive clamp
        s_idx[i] = v;
    }
    for (int i = tid; i < M; i += NT) {
        int node = node0 + i; if (node >= NN) node = NN - 1;
        s_deg[i] = deg[node];
    }
    for (int i = tid; i < M * LDA; i += NT) s_h[i] = (bf16_t)0.0f;

    // per-lane gate biases (bih+bhh), col = this lane's D-layout column
    float gb[2][4];
    #pragma unroll
    for (int ct = 0; ct < 2; ++ct)
        #pragma unroll
        for (int g = 0; g < 4; ++g) {
            int gcol = g * F + wave * 32 + ct * 16 + m16;
            gb[ct][g] = bih[gcol] + bhh[gcol];
        }

    __syncthreads();

    // per-lane degrees for the D-layout rows this lane owns
    int dg[2][4];
    #pragma unroll
    for (int rt = 0; rt < 2; ++rt)
        #pragma unroll
        for (int r = 0; r < 4; ++r)
            dg[rt][r] = s_deg[rt * 16 + q * 4 + r];

    // staging helper: row -> s_x[m], converting f32->bf16 if XF32
    auto stage_row = [&](int m, int sub, int row) {
        if constexpr (XF32) {
            const float* p = (const float*)xsrc_v + (size_t)row * F + sub * 16;
            float4 f0 = reinterpret_cast<const float4*>(p)[0];
            float4 f1 = reinterpret_cast<const float4*>(p)[1];
            float4 f2 = reinterpret_cast<const float4*>(p)[2];
            float4 f3 = reinterpret_cast<const float4*>(p)[3];
            bf16_t t[16] __attribute__((aligned(16)));
            t[0]=(bf16_t)f0.x; t[1]=(bf16_t)f0.y; t[2]=(bf16_t)f0.z; t[3]=(bf16_t)f0.w;
            t[4]=(bf16_t)f1.x; t[5]=(bf16_t)f1.y; t[6]=(bf16_t)f1.z; t[7]=(bf16_t)f1.w;
            t[8]=(bf16_t)f2.x; t[9]=(bf16_t)f2.y; t[10]=(bf16_t)f2.z; t[11]=(bf16_t)f2.w;
            t[12]=(bf16_t)f3.x; t[13]=(bf16_t)f3.y; t[14]=(bf16_t)f3.z; t[15]=(bf16_t)f3.w;
            uint4* dst = reinterpret_cast<uint4*>(&s_x[m * LDA + sub * 16]);
            dst[0] = reinterpret_cast<const uint4*>(t)[0];
            dst[1] = reinterpret_cast<const uint4*>(t)[1];
        } else {
            const bf16_t* p = (const bf16_t*)xsrc_v + (size_t)row * F + sub * 16;
            uint4 a = reinterpret_cast<const uint4*>(p)[0];
            uint4 b = reinterpret_cast<const uint4*>(p)[1];
            uint4* dst = reinterpret_cast<uint4*>(&s_x[m * LDA + sub * 16]);
            dst[0] = a; dst[1] = b;
        }
    };

    {   // stage x for t=0 (gathered neighbor rows)
        int m = tid / TPR, sub = tid % TPR;
        stage_row(m, sub, s_idx[m * DMAXX + 0]);
    }

    f32x4 c_[2][2];
    #pragma unroll
    for (int rt = 0; rt < 2; ++rt)
        #pragma unroll
        for (int ct = 0; ct < 2; ++ct)
            #pragma unroll
            for (int r = 0; r < 4; ++r) c_[rt][ct][r] = 0.0f;

    __syncthreads();

    #pragma unroll 1
    for (int t = 0; t < DMAXX; ++t) {
        // gates[32, 4F] = x_t @ Wih^T + h @ Whh^T + (bih+bhh)
        f32x4 acc[2][2][4];
        #pragma unroll
        for (int rt = 0; rt < 2; ++rt)
          #pragma unroll
          for (int ct = 0; ct < 2; ++ct)
            #pragma unroll
            for (int g = 0; g < 4; ++g)
              #pragma unroll
              for (int r = 0; r < 4; ++r) acc[rt][ct][g][r] = gb[ct][g];

        #pragma unroll
        for (int kk = 0; kk < KK; ++kk) {
            const int ko = kk * 32 + q * 8;
            bf16x8 ax0 = *reinterpret_cast<const bf16x8*>(&s_x[m16 * LDA + ko]);
            bf16x8 ax1 = *reinterpret_cast<const bf16x8*>(&s_x[(16 + m16) * LDA + ko]);
            bf16x8 ah0 = *reinterpret_cast<const bf16x8*>(&s_h[m16 * LDA + ko]);
            bf16x8 ah1 = *reinterpret_cast<const bf16x8*>(&s_h[(16 + m16) * LDA + ko]);
            #pragma unroll
            for (int g = 0; g < 4; ++g) {
                #pragma unroll
                for (int ct = 0; ct < 2; ++ct) {
                    const size_t wrow = (size_t)(g * F + wave * 32 + ct * 16 + m16) * F + ko;
                    bf16x8 bx = *reinterpret_cast<const bf16x8*>(Wih + wrow);
                    bf16x8 bh = *reinterpret_cast<const bf16x8*>(Whh + wrow);
                    acc[0][ct][g] = __builtin_amdgcn_mfma_f32_16x16x32_bf16(ax0, bx, acc[0][ct][g], 0, 0, 0);
                    acc[1][ct][g] = __builtin_amdgcn_mfma_f32_16x16x32_bf16(ax1, bx, acc[1][ct][g], 0, 0, 0);
                    acc[0][ct][g] = __builtin_amdgcn_mfma_f32_16x16x32_bf16(ah0, bh, acc[0][ct][g], 0, 0, 0);
                    acc[1][ct][g] = __builtin_amdgcn_mfma_f32_16x16x32_bf16(ah1, bh, acc[1][ct][g], 0, 0, 0);
                }
            }
        }

        // pointwise LSTM update; lane holds i,f,g,o for its (row,col) pairs
        float hn[2][2][4];
        #pragma unroll
        for (int rt = 0; rt < 2; ++rt)
          #pragma unroll
          for (int ct = 0; ct < 2; ++ct)
            #pragma unroll
            for (int r = 0; r < 4; ++r) {
                float iv = fsig(acc[rt][ct][0][r]);
                float fv = fsig(acc[rt][ct][1][r]);
                float gv = ftanh(acc[rt][ct][2][r]);
                float ov = fsig(acc[rt][ct][3][r]);
                float cn = fv * c_[rt][ct][r] + iv * gv;
                float hv = ov * ftanh(cn);
                if (t < dg[rt][r]) c_[rt][ct][r] = cn;   // masked: t >= deg keeps state
                hn[rt][ct][r] = hv;
            }

        __syncthreads();   // all LDS reads for step t done

        // masked h writeback (skip store when t >= deg -> old h survives)
        #pragma unroll
        for (int rt = 0; rt < 2; ++rt)
          #pragma unroll
          for (int ct = 0; ct < 2; ++ct)
            #pragma unroll
            for (int r = 0; r < 4; ++r)
                if (t < dg[rt][r])
                    s_h[(rt * 16 + q * 4 + r) * LDA + wave * 32 + ct * 16 + m16] =
                        (bf16_t)hn[rt][ct][r];

        {   // stage x for t+1; on the last step stage SELF rows for the epilogue
            int m = tid / TPR, sub = tid % TPR;
            int row;
            if (t + 1 < DMAXX) row = s_idx[m * DMAXX + t + 1];
            else { row = node0 + m; if (row >= NN) row = NN - 1; }
            stage_row(m, sub, row);
        }
        __syncthreads();
    }

    // epilogue: out = x_self @ Wself^T + h_final @ Wneigh^T + bout (+relu)
    constexpr int TILES = (OUTF / 16) * 2;
    constexpr int TPW = TILES / NW;
    static_assert(TILES % NW == 0, "tile split must be even across waves");
    #pragma unroll
    for (int tt = 0; tt < TPW; ++tt) {
        int tile = wave * TPW + tt;
        int rt = tile & 1, oct = tile >> 1;
        f32x4 o;
        o[0] = 0.f; o[1] = 0.f; o[2] = 0.f; o[3] = 0.f;
        #pragma unroll
        for (int kk = 0; kk < KK; ++kk) {
            const int ko = kk * 32 + q * 8;
            bf16x8 axs = *reinterpret_cast<const bf16x8*>(&s_x[(rt * 16 + m16) * LDA + ko]);
            bf16x8 am  = *reinterpret_cast<const bf16x8*>(&s_h[(rt * 16 + m16) * LDA + ko]);
            const size_t orow = (size_t)(oct * 16 + m16) * F + ko;
            bf16x8 bs = *reinterpret_cast<const bf16x8*>(Wself + orow);
            bf16x8 bn = *reinterpret_cast<const bf16x8*>(Wneigh + orow);
            o = __builtin_amdgcn_mfma_f32_16x16x32_bf16(axs, bs, o, 0, 0, 0);
            o = __builtin_amdgcn_mfma_f32_16x16x32_bf16(am, bn, o, 0, 0, 0);
        }
        int ocol = oct * 16 + m16;
        float bias = bout[ocol];
        #pragma unroll
        for (int r = 0; r < 4; ++r) {
            int node = node0 + rt * 16 + q * 4 + r;
            if (node < NN) {
                float v = o[r] + bias;
                if (RELU) v = fmaxf(v, 0.0f);
                outp[(size_t)node * OUTF + ocol] = (OutT)v;
            }
        }
    }
}

extern "C" void kernel_launch(void* const* d_in, const int* in_sizes, int n_in,
                              void* d_out, int out_size, void* d_ws, size_t ws_size,
                              hipStream_t stream)
{
    const float* feat    = (const float*)d_in[0];
    const int*   nbr     = (const int*)d_in[1];
    const int*   degp    = (const int*)d_in[2];
    const float* Wih1    = (const float*)d_in[3];
    const float* Whh1    = (const float*)d_in[4];
    const float* bih1    = (const float*)d_in[5];
    const float* bhh1    = (const float*)d_in[6];
    const float* Wself1  = (const float*)d_in[7];
    const float* Wneigh1 = (const float*)d_in[8];
    const float* b1      = (const float*)d_in[9];
    const float* Wih2    = (const float*)d_in[10];
    const float* Whh2    = (const float*)d_in[11];
    const float* bih2    = (const float*)d_in[12];
    const float* bhh2    = (const float*)d_in[13];
    const float* Wself2  = (const float*)d_in[14];
    const float* Wneigh2 = (const float*)d_in[15];
    const float* b2      = (const float*)d_in[16];

    bf16_t* hglob;  hipGetSymbolAddress((void**)&hglob, HIP_SYMBOL(g_hbuf));
    bf16_t* wglob;  hipGetSymbolAddress((void**)&wglob, HIP_SYMBOL(g_wbuf));

    cvt_weights<<<W_TOTAL / 4 / 256, 256, 0, stream>>>(
        Wih1, Whh1, Wself1, Wneigh1, Wih2, Whh2, Wself2, Wneigh2);

    const int grid = (NN + 31) / 32;   // 938 WGs
    sage_layer<128, 256, 4, true, true, bf16_t><<<grid, 256, 0, stream>>>(
        feat, nbr, degp,
        wglob + OFF_WIH1, wglob + OFF_WHH1, bih1, bhh1,
        wglob + OFF_WSELF1, wglob + OFF_WNEIGH1, b1, hglob);
    sage_layer<256, 64, 8, false, false, float><<<grid, 512, 0, stream>>>(
        hglob, nbr, degp,
        wglob + OFF_WIH2, wglob + OFF_WHH2, bih2, bhh2,
        wglob + OFF_WSELF2, wglob + OFF_WNEIGH2, b2, (float*)d_out);
}

// Round 4
// 2349.605 us; speedup vs baseline: 1.3888x; 1.3888x over previous
//
#include <hip/hip_runtime.h>
#include <hip/hip_bf16.h>
#include <stdint.h>

// SAGE (GraphSAGE, LSTM aggregator). f32 I/O, bf16-granularity comparison ->
// bf16 MFMA internally. N=30000, DMAX=16, dims 128 -> 256 -> 64.
// R3 -> R4 (R3: passed, 3263us, layer2 FETCH 7.1GB, MfmaUtil 6.9% = L2-miss bound):
//   1. Precompute xg[N,4F] = x @ Wih^T + bih + bhh as a dense GEMM (each node
//      row was re-multiplied ~16x as a neighbor). Stored bf16 GATE-INTERLEAVED
//      ([c][g]) so recurrence acc-init is one ushort4 (8B) gather per col.
//      Recurrence streams only Whh -> weight request volume halves; FLOPs halve.
//   2. M=64 node tiles in recurrence (halves WG count -> halves weight traffic
//      again; 1 WG/CU puts XCD CUs in loose lockstep on the same Whh -> L2 hits).
//      ct-outer loop keeps peak VGPR ~210 (<256 needed for 512-thr WG).
// Verified layouts (learn_hip m89/m91): A[m=lane&15][k=q*8+j],
// D[row=q*4+r][col=lane&15]; W[4F,F] row-major == gemm-BT B-frag layout.

#define NN 30000
#define DMAXX 16

typedef __bf16 bf16_t;
typedef __bf16 bf16x8 __attribute__((ext_vector_type(8)));
typedef float f32x4 __attribute__((ext_vector_type(4)));

// persistent scratch (fully rewritten every call; no cross-call state reuse)
__device__ __align__(16) bf16_t g_hbuf[(size_t)NN * 256];    // layer-1 output h1
__device__ __align__(16) bf16_t g_xg1[(size_t)NN * 512];     // feat@Wih1^T + biases
__device__ __align__(16) bf16_t g_xg2[(size_t)NN * 1024];    // h1@Wih2^T + biases
__device__ __align__(16) bf16_t g_wbuf[753664];              // bf16 weight copies

#define OFF_WIH1 0
#define OFF_WHH1 65536
#define OFF_WSELF1 131072
#define OFF_WNEIGH1 163840
#define OFF_WIH2 196608
#define OFF_WHH2 458752
#define OFF_WSELF2 720896
#define OFF_WNEIGH2 737280
#define W_TOTAL 753664

__global__ __launch_bounds__(256)
void cvt_weights(const float* __restrict__ s0, const float* __restrict__ s1,
                 const float* __restrict__ s2, const float* __restrict__ s3,
                 const float* __restrict__ s4, const float* __restrict__ s5,
                 const float* __restrict__ s6, const float* __restrict__ s7)
{
    int i = (blockIdx.x * 256 + threadIdx.x) * 4;
    if (i >= W_TOTAL) return;
    const float* src; int off;
    if      (i < OFF_WHH1)   { src = s0; off = OFF_WIH1; }
    else if (i < OFF_WSELF1) { src = s1; off = OFF_WHH1; }
    else if (i < OFF_WNEIGH1){ src = s2; off = OFF_WSELF1; }
    else if (i < OFF_WIH2)   { src = s3; off = OFF_WNEIGH1; }
    else if (i < OFF_WHH2)   { src = s4; off = OFF_WIH2; }
    else if (i < OFF_WSELF2) { src = s5; off = OFF_WHH2; }
    else if (i < OFF_WNEIGH2){ src = s6; off = OFF_WSELF2; }
    else                     { src = s7; off = OFF_WNEIGH2; }
    float4 v = *reinterpret_cast<const float4*>(src + (i - off));
    bf16_t o[4] __attribute__((aligned(8)));
    o[0] = (bf16_t)v.x; o[1] = (bf16_t)v.y; o[2] = (bf16_t)v.z; o[3] = (bf16_t)v.w;
    *reinterpret_cast<uint2*>(&g_wbuf[i]) = *reinterpret_cast<const uint2*>(o);
}

__device__ __forceinline__ float fsig(float x) { return 1.0f / (1.0f + __expf(-x)); }
__device__ __forceinline__ float ftanh(float x) { return 1.0f - 2.0f / (__expf(2.0f * x) + 1.0f); }
__device__ __forceinline__ float bf2f(unsigned short s) {
    union { unsigned u; float f; } v; v.u = ((unsigned)s) << 16; return v.f;
}

// stage a 64-row x-tile (global, row-clamped) into LDS as bf16
template<int F, int LDA, int NT, bool XF32>
__device__ __forceinline__ void stage_tile(bf16_t* dst, const void* src, int row0, int tid)
{
    constexpr int UN = F / 8;          // 16B(bf16) units per row
    for (int e = tid; e < 64 * UN; e += NT) {
        int m = e / UN, sub = e - m * UN;
        int row = row0 + m; if (row >= NN) row = NN - 1;
        if constexpr (XF32) {
            const float* p = (const float*)src + (size_t)row * F + sub * 8;
            float4 f0 = reinterpret_cast<const float4*>(p)[0];
            float4 f1 = reinterpret_cast<const float4*>(p)[1];
            bf16_t t[8] __attribute__((aligned(16)));
            t[0]=(bf16_t)f0.x; t[1]=(bf16_t)f0.y; t[2]=(bf16_t)f0.z; t[3]=(bf16_t)f0.w;
            t[4]=(bf16_t)f1.x; t[5]=(bf16_t)f1.y; t[6]=(bf16_t)f1.z; t[7]=(bf16_t)f1.w;
            *reinterpret_cast<uint4*>(&dst[m * LDA + sub * 8]) = *reinterpret_cast<const uint4*>(t);
        } else {
            const bf16_t* p = (const bf16_t*)src + (size_t)row * F + sub * 8;
            *reinterpret_cast<uint4*>(&dst[m * LDA + sub * 8]) = *reinterpret_cast<const uint4*>(p);
        }
    }
}

// xg[N, 4F] (gate-interleaved [c][g]) = x[N,F] @ W[4F,F]^T + b0 + b1
template<int F, int G, int NW, bool XF32>
__global__ __launch_bounds__(NW * 64)
void xg_gemm(const void* __restrict__ xsrc_v, const bf16_t* __restrict__ W,
             const float* __restrict__ b0, const float* __restrict__ b1v,
             bf16_t* __restrict__ xg)
{
    constexpr int LDA = F + 8, KK = F / 32, NT = NW * 64;
    constexpr int CPW = G / NW;        // linear out-cols per wave
    constexpr int CT = CPW / 16;
    static_assert(CPW % 16 == 0 && F % 16 == 0, "");
    const int tid = threadIdx.x, wave = tid >> 6, lane = tid & 63;
    const int q = lane >> 4, m16 = lane & 15;
    const int row0 = blockIdx.x * 64;

    __shared__ __align__(16) bf16_t s_x[64 * LDA];
    stage_tile<F, LDA, NT, XF32>(s_x, xsrc_v, row0, tid);
    __syncthreads();

    #pragma unroll
    for (int ct = 0; ct < CT; ++ct) {
        const int lc0 = wave * CPW + ct * 16;   // linear col block (within one gate)
        const int g = lc0 / F, c0 = lc0 - g * F;
        const float bias = b0[lc0 + m16] + b1v[lc0 + m16];
        f32x4 acc[4];
        #pragma unroll
        for (int rt = 0; rt < 4; ++rt)
            #pragma unroll
            for (int r = 0; r < 4; ++r) acc[rt][r] = bias;
        #pragma unroll
        for (int kk = 0; kk < KK; ++kk) {
            const int ko = kk * 32 + q * 8;
            bf16x8 b = *reinterpret_cast<const bf16x8*>(W + (size_t)(lc0 + m16) * F + ko);
            #pragma unroll
            for (int rt = 0; rt < 4; ++rt) {
                bf16x8 a = *reinterpret_cast<const bf16x8*>(&s_x[(rt * 16 + m16) * LDA + ko]);
                acc[rt] = __builtin_amdgcn_mfma_f32_16x16x32_bf16(a, b, acc[rt], 0, 0, 0);
            }
        }
        #pragma unroll
        for (int rt = 0; rt < 4; ++rt)
            #pragma unroll
            for (int r = 0; r < 4; ++r) {
                int row = row0 + rt * 16 + q * 4 + r;
                if (row < NN)
                    xg[(size_t)row * G + (size_t)(c0 + m16) * 4 + g] = (bf16_t)acc[rt][r];
            }
    }
}

// LSTM recurrence over gathered neighbors + fused fc epilogue.
// gates = gather(xg) + h @ Whh^T ; out = x_self@Wself^T + h_fin@Wneigh^T + b
template<int F, int NW, int OUTF, bool RELU, bool XF32, typename OutT>
__global__ __launch_bounds__(NW * 64)
void sage_rec(const void* __restrict__ xself_v,
              const bf16_t* __restrict__ xg,
              const int* __restrict__ nbr_idx, const int* __restrict__ deg,
              const bf16_t* __restrict__ Whh,
              const bf16_t* __restrict__ Wself, const bf16_t* __restrict__ Wneigh,
              const float* __restrict__ bout, OutT* __restrict__ outp)
{
    constexpr int M = 64, RT = 4, LDA = F + 8, KK = F / 32, NT = NW * 64;
    constexpr int CPW = F / NW, CT = CPW / 16, G4 = 4 * F;
    static_assert(CPW % 16 == 0, "");
    const int tid = threadIdx.x, wave = tid >> 6, lane = tid & 63;
    const int q = lane >> 4, m16 = lane & 15;
    const int node0 = blockIdx.x * M;

    __shared__ __align__(16) bf16_t s_h[M * LDA];
    __shared__ __align__(16) bf16_t s_x[M * LDA];
    __shared__ int s_idx[M * DMAXX];
    __shared__ int s_deg[M];

    for (int i = tid; i < M * DMAXX; i += NT) {
        int m = i >> 4;
        int node = node0 + m; if (node >= NN) node = NN - 1;
        int v = nbr_idx[node * DMAXX + (i & 15)];
        if (v < 0) v = 0; if (v >= NN) v = NN - 1;
        s_idx[i] = v;
    }
    for (int i = tid; i < M; i += NT) {
        int node = node0 + i; if (node >= NN) node = NN - 1;
        s_deg[i] = deg[node];
    }
    for (int i = tid; i < M * LDA; i += NT) s_h[i] = (bf16_t)0.0f;
    stage_tile<F, LDA, NT, XF32>(s_x, xself_v, node0, tid);   // own rows, for epilogue
    __syncthreads();

    int dg[RT][4];
    #pragma unroll
    for (int rt = 0; rt < RT; ++rt)
        #pragma unroll
        for (int r = 0; r < 4; ++r)
            dg[rt][r] = s_deg[rt * 16 + q * 4 + r];

    f32x4 c_[RT][CT];
    #pragma unroll
    for (int rt = 0; rt < RT; ++rt)
        #pragma unroll
        for (int ct = 0; ct < CT; ++ct)
            #pragma unroll
            for (int r = 0; r < 4; ++r) c_[rt][ct][r] = 0.0f;

    float hn[RT][CT][4];

    #pragma unroll 1
    for (int t = 0; t < DMAXX; ++t) {
        #pragma unroll
        for (int ct = 0; ct < CT; ++ct) {
            // gather gate-init (xg includes x@Wih^T + both biases), 8B/elem
            ushort4 u[RT][4];
            #pragma unroll
            for (int rt = 0; rt < RT; ++rt)
                #pragma unroll
                for (int r = 0; r < 4; ++r) {
                    int row = s_idx[(rt * 16 + q * 4 + r) * DMAXX + t];
                    u[rt][r] = *reinterpret_cast<const ushort4*>(
                        xg + (size_t)row * G4 + (size_t)(wave * CPW + ct * 16 + m16) * 4);
                }
            f32x4 acc[RT][4];
            #pragma unroll
            for (int rt = 0; rt < RT; ++rt)
                #pragma unroll
                for (int g = 0; g < 4; ++g)
                    #pragma unroll
                    for (int r = 0; r < 4; ++r) acc[rt][g][r] = 0.0f;
            #pragma unroll
            for (int kk = 0; kk < KK; ++kk) {
                const int ko = kk * 32 + q * 8;
                bf16x8 ah[RT];
                #pragma unroll
                for (int rt = 0; rt < RT; ++rt)
                    ah[rt] = *reinterpret_cast<const bf16x8*>(&s_h[(rt * 16 + m16) * LDA + ko]);
                #pragma unroll
                for (int g = 0; g < 4; ++g) {
                    bf16x8 bh = *reinterpret_cast<const bf16x8*>(
                        Whh + (size_t)(g * F + wave * CPW + ct * 16 + m16) * F + ko);
                    #pragma unroll
                    for (int rt = 0; rt < RT; ++rt)
                        acc[rt][g] = __builtin_amdgcn_mfma_f32_16x16x32_bf16(ah[rt], bh, acc[rt][g], 0, 0, 0);
                }
            }
            // pointwise LSTM update for this col-tile
            #pragma unroll
            for (int rt = 0; rt < RT; ++rt)
                #pragma unroll
                for (int r = 0; r < 4; ++r) {
                    float iv = fsig (acc[rt][0][r] + bf2f(u[rt][r].x));
                    float fv = fsig (acc[rt][1][r] + bf2f(u[rt][r].y));
                    float gv = ftanh(acc[rt][2][r] + bf2f(u[rt][r].z));
                    float ov = fsig (acc[rt][3][r] + bf2f(u[rt][r].w));
                    float cn = fv * c_[rt][ct][r] + iv * gv;
                    float hv = ov * ftanh(cn);
                    if (t < dg[rt][r]) c_[rt][ct][r] = cn;  // t >= deg: state untouched
                    hn[rt][ct][r] = hv;
                }
        }
        __syncthreads();   // all s_h reads for step t complete
        #pragma unroll
        for (int rt = 0; rt < RT; ++rt)
            #pragma unroll
            for (int ct = 0; ct < CT; ++ct)
                #pragma unroll
                for (int r = 0; r < 4; ++r)
                    if (t < dg[rt][r])
                        s_h[(rt * 16 + q * 4 + r) * LDA + wave * CPW + ct * 16 + m16] =
                            (bf16_t)hn[rt][ct][r];
        __syncthreads();
    }

    // epilogue: out = x_self @ Wself^T + h_fin @ Wneigh^T + bout (+relu)
    constexpr int NCT = OUTF / 16;
    constexpr int TILES = NCT * RT;
    constexpr int TPW = TILES / NW;
    static_assert(TILES % NW == 0, "");
    #pragma unroll
    for (int tt = 0; tt < TPW; ++tt) {
        int tile = wave * TPW + tt;
        int ot = tile % NCT, rt = tile / NCT;
        f32x4 o;
        o[0] = 0.f; o[1] = 0.f; o[2] = 0.f; o[3] = 0.f;
        #pragma unroll
        for (int kk = 0; kk < KK; ++kk) {
            const int ko = kk * 32 + q * 8;
            bf16x8 axs = *reinterpret_cast<const bf16x8*>(&s_x[(rt * 16 + m16) * LDA + ko]);
            bf16x8 am  = *reinterpret_cast<const bf16x8*>(&s_h[(rt * 16 + m16) * LDA + ko]);
            bf16x8 bs = *reinterpret_cast<const bf16x8*>(Wself  + (size_t)(ot * 16 + m16) * F + ko);
            bf16x8 bn = *reinterpret_cast<const bf16x8*>(Wneigh + (size_t)(ot * 16 + m16) * F + ko);
            o = __builtin_amdgcn_mfma_f32_16x16x32_bf16(axs, bs, o, 0, 0, 0);
            o = __builtin_amdgcn_mfma_f32_16x16x32_bf16(am,  bn, o, 0, 0, 0);
        }
        int ocol = ot * 16 + m16;
        float bias = bout[ocol];
        #pragma unroll
        for (int r = 0; r < 4; ++r) {
            int node = node0 + rt * 16 + q * 4 + r;
            if (node < NN) {
                float v = o[r] + bias;
                if (RELU) v = fmaxf(v, 0.0f);
                outp[(size_t)node * OUTF + ocol] = (OutT)v;
            }
        }
    }
}

extern "C" void kernel_launch(void* const* d_in, const int* in_sizes, int n_in,
                              void* d_out, int out_size, void* d_ws, size_t ws_size,
                              hipStream_t stream)
{
    const float* feat    = (const float*)d_in[0];
    const int*   nbr     = (const int*)d_in[1];
    const int*   degp    = (const int*)d_in[2];
    const float* Wih1    = (const float*)d_in[3];
    const float* Whh1    = (const float*)d_in[4];
    const float* bih1    = (const float*)d_in[5];
    const float* bhh1    = (const float*)d_in[6];
    const float* Wself1  = (const float*)d_in[7];
    const float* Wneigh1 = (const float*)d_in[8];
    const float* b1      = (const float*)d_in[9];
    const float* Wih2    = (const float*)d_in[10];
    const float* Whh2    = (const float*)d_in[11];
    const float* bih2    = (const float*)d_in[12];
    const float* bhh2    = (const float*)d_in[13];
    const float* Wself2  = (const float*)d_in[14];
    const float* Wneigh2 = (const float*)d_in[15];
    const float* b2      = (const float*)d_in[16];

    bf16_t *hglob, *wglob, *xg1, *xg2;
    hipGetSymbolAddress((void**)&hglob, HIP_SYMBOL(g_hbuf));
    hipGetSymbolAddress((void**)&wglob, HIP_SYMBOL(g_wbuf));
    hipGetSymbolAddress((void**)&xg1,   HIP_SYMBOL(g_xg1));
    hipGetSymbolAddress((void**)&xg2,   HIP_SYMBOL(g_xg2));

    cvt_weights<<<W_TOTAL / 4 / 256, 256, 0, stream>>>(
        Wih1, Whh1, Wself1, Wneigh1, Wih2, Whh2, Wself2, Wneigh2);

    const int grid = (NN + 63) / 64;   // 469 WGs

    xg_gemm<128, 512, 8, true><<<grid, 512, 0, stream>>>(
        feat, wglob + OFF_WIH1, bih1, bhh1, xg1);

    sage_rec<128, 8, 256, true, true, bf16_t><<<grid, 512, 0, stream>>>(
        feat, xg1, nbr, degp, wglob + OFF_WHH1,
        wglob + OFF_WSELF1, wglob + OFF_WNEIGH1, b1, hglob);

    xg_gemm<256, 1024, 8, false><<<grid, 512, 0, stream>>>(
        hglob, wglob + OFF_WIH2, bih2, bhh2, xg2);

    sage_rec<256, 8, 64, false, false, float><<<grid, 512, 0, stream>>>(
        hglob, xg2, nbr, degp, wglob + OFF_WHH2,
        wglob + OFF_WSELF2, wglob + OFF_WNEIGH2, b2, (float*)d_out);
}

// Round 5
// 2333.682 us; speedup vs baseline: 1.3982x; 1.0068x over previous
//
#include <hip/hip_runtime.h>
#include <hip/hip_bf16.h>
#include <stdint.h>

// SAGE (GraphSAGE, LSTM aggregator). f32 I/O, bf16-granularity comparison ->
// bf16 MFMA internally. N=30000, DMAX=16, dims 128 -> 256 -> 64.
// R4 -> R5 (R4: passed 2350us; layer2 rec 1908us, WRITE_SIZE 1.7GB on a 7.7MB
// output = REGISTER SPILLS (VGPR capped at 128 vs ~220 live), FETCH 3.4GB):
//   1. __launch_bounds__(512, 2): VGPR cap 256 -> no spills. 1 WG/CU resident.
//   2. Nontemporal gather loads (xg) so the random gather stream stops
//      evicting the L2-resident Whh weight working set.
// Verified layouts (learn_hip m89/m91): A[m=lane&15][k=q*8+j],
// D[row=q*4+r][col=lane&15]; W[4F,F] row-major == gemm-BT B-frag layout.

#define NN 30000
#define DMAXX 16

typedef __bf16 bf16_t;
typedef __bf16 bf16x8 __attribute__((ext_vector_type(8)));
typedef float f32x4 __attribute__((ext_vector_type(4)));
typedef unsigned short u16x4 __attribute__((ext_vector_type(4)));

// persistent scratch (fully rewritten every call; no cross-call state reuse)
__device__ __align__(16) bf16_t g_hbuf[(size_t)NN * 256];    // layer-1 output h1
__device__ __align__(16) bf16_t g_xg1[(size_t)NN * 512];     // feat@Wih1^T + biases
__device__ __align__(16) bf16_t g_xg2[(size_t)NN * 1024];    // h1@Wih2^T + biases
__device__ __align__(16) bf16_t g_wbuf[753664];              // bf16 weight copies

#define OFF_WIH1 0
#define OFF_WHH1 65536
#define OFF_WSELF1 131072
#define OFF_WNEIGH1 163840
#define OFF_WIH2 196608
#define OFF_WHH2 458752
#define OFF_WSELF2 720896
#define OFF_WNEIGH2 737280
#define W_TOTAL 753664

__global__ __launch_bounds__(256)
void cvt_weights(const float* __restrict__ s0, const float* __restrict__ s1,
                 const float* __restrict__ s2, const float* __restrict__ s3,
                 const float* __restrict__ s4, const float* __restrict__ s5,
                 const float* __restrict__ s6, const float* __restrict__ s7)
{
    int i = (blockIdx.x * 256 + threadIdx.x) * 4;
    if (i >= W_TOTAL) return;
    const float* src; int off;
    if      (i < OFF_WHH1)   { src = s0; off = OFF_WIH1; }
    else if (i < OFF_WSELF1) { src = s1; off = OFF_WHH1; }
    else if (i < OFF_WNEIGH1){ src = s2; off = OFF_WSELF1; }
    else if (i < OFF_WIH2)   { src = s3; off = OFF_WNEIGH1; }
    else if (i < OFF_WHH2)   { src = s4; off = OFF_WIH2; }
    else if (i < OFF_WSELF2) { src = s5; off = OFF_WHH2; }
    else if (i < OFF_WNEIGH2){ src = s6; off = OFF_WSELF2; }
    else                     { src = s7; off = OFF_WNEIGH2; }
    float4 v = *reinterpret_cast<const float4*>(src + (i - off));
    bf16_t o[4] __attribute__((aligned(8)));
    o[0] = (bf16_t)v.x; o[1] = (bf16_t)v.y; o[2] = (bf16_t)v.z; o[3] = (bf16_t)v.w;
    *reinterpret_cast<uint2*>(&g_wbuf[i]) = *reinterpret_cast<const uint2*>(o);
}

__device__ __forceinline__ float fsig(float x) { return 1.0f / (1.0f + __expf(-x)); }
__device__ __forceinline__ float ftanh(float x) { return 1.0f - 2.0f / (__expf(2.0f * x) + 1.0f); }
__device__ __forceinline__ float bf2f(unsigned short s) {
    union { unsigned u; float f; } v; v.u = ((unsigned)s) << 16; return v.f;
}

// stage a 64-row x-tile (global, row-clamped) into LDS as bf16
template<int F, int LDA, int NT, bool XF32>
__device__ __forceinline__ void stage_tile(bf16_t* dst, const void* src, int row0, int tid)
{
    constexpr int UN = F / 8;          // 16B(bf16) units per row
    for (int e = tid; e < 64 * UN; e += NT) {
        int m = e / UN, sub = e - m * UN;
        int row = row0 + m; if (row >= NN) row = NN - 1;
        if constexpr (XF32) {
            const float* p = (const float*)src + (size_t)row * F + sub * 8;
            float4 f0 = reinterpret_cast<const float4*>(p)[0];
            float4 f1 = reinterpret_cast<const float4*>(p)[1];
            bf16_t t[8] __attribute__((aligned(16)));
            t[0]=(bf16_t)f0.x; t[1]=(bf16_t)f0.y; t[2]=(bf16_t)f0.z; t[3]=(bf16_t)f0.w;
            t[4]=(bf16_t)f1.x; t[5]=(bf16_t)f1.y; t[6]=(bf16_t)f1.z; t[7]=(bf16_t)f1.w;
            *reinterpret_cast<uint4*>(&dst[m * LDA + sub * 8]) = *reinterpret_cast<const uint4*>(t);
        } else {
            const bf16_t* p = (const bf16_t*)src + (size_t)row * F + sub * 8;
            *reinterpret_cast<uint4*>(&dst[m * LDA + sub * 8]) = *reinterpret_cast<const uint4*>(p);
        }
    }
}

// xg[N, 4F] (gate-interleaved [c][g]) = x[N,F] @ W[4F,F]^T + b0 + b1
template<int F, int G, int NW, bool XF32>
__global__ __launch_bounds__(NW * 64, 2)
void xg_gemm(const void* __restrict__ xsrc_v, const bf16_t* __restrict__ W,
             const float* __restrict__ b0, const float* __restrict__ b1v,
             bf16_t* __restrict__ xg)
{
    constexpr int LDA = F + 8, KK = F / 32, NT = NW * 64;
    constexpr int CPW = G / NW;        // linear out-cols per wave
    constexpr int CT = CPW / 16;
    static_assert(CPW % 16 == 0 && F % 16 == 0, "");
    const int tid = threadIdx.x, wave = tid >> 6, lane = tid & 63;
    const int q = lane >> 4, m16 = lane & 15;
    const int row0 = blockIdx.x * 64;

    __shared__ __align__(16) bf16_t s_x[64 * LDA];
    stage_tile<F, LDA, NT, XF32>(s_x, xsrc_v, row0, tid);
    __syncthreads();

    #pragma unroll
    for (int ct = 0; ct < CT; ++ct) {
        const int lc0 = wave * CPW + ct * 16;   // linear col block (within one gate)
        const int g = lc0 / F, c0 = lc0 - g * F;
        const float bias = b0[lc0 + m16] + b1v[lc0 + m16];
        f32x4 acc[4];
        #pragma unroll
        for (int rt = 0; rt < 4; ++rt)
            #pragma unroll
            for (int r = 0; r < 4; ++r) acc[rt][r] = bias;
        #pragma unroll
        for (int kk = 0; kk < KK; ++kk) {
            const int ko = kk * 32 + q * 8;
            bf16x8 b = *reinterpret_cast<const bf16x8*>(W + (size_t)(lc0 + m16) * F + ko);
            #pragma unroll
            for (int rt = 0; rt < 4; ++rt) {
                bf16x8 a = *reinterpret_cast<const bf16x8*>(&s_x[(rt * 16 + m16) * LDA + ko]);
                acc[rt] = __builtin_amdgcn_mfma_f32_16x16x32_bf16(a, b, acc[rt], 0, 0, 0);
            }
        }
        #pragma unroll
        for (int rt = 0; rt < 4; ++rt)
            #pragma unroll
            for (int r = 0; r < 4; ++r) {
                int row = row0 + rt * 16 + q * 4 + r;
                if (row < NN)
                    xg[(size_t)row * G + (size_t)(c0 + m16) * 4 + g] = (bf16_t)acc[rt][r];
            }
    }
}

// LSTM recurrence over gathered neighbors + fused fc epilogue.
// gates = gather(xg) + h @ Whh^T ; out = x_self@Wself^T + h_fin@Wneigh^T + b
template<int F, int NW, int OUTF, bool RELU, bool XF32, typename OutT>
__global__ __launch_bounds__(NW * 64, 2)
void sage_rec(const void* __restrict__ xself_v,
              const bf16_t* __restrict__ xg,
              const int* __restrict__ nbr_idx, const int* __restrict__ deg,
              const bf16_t* __restrict__ Whh,
              const bf16_t* __restrict__ Wself, const bf16_t* __restrict__ Wneigh,
              const float* __restrict__ bout, OutT* __restrict__ outp)
{
    constexpr int M = 64, RT = 4, LDA = F + 8, KK = F / 32, NT = NW * 64;
    constexpr int CPW = F / NW, CT = CPW / 16, G4 = 4 * F;
    static_assert(CPW % 16 == 0, "");
    const int tid = threadIdx.x, wave = tid >> 6, lane = tid & 63;
    const int q = lane >> 4, m16 = lane & 15;
    const int node0 = blockIdx.x * M;

    __shared__ __align__(16) bf16_t s_h[M * LDA];
    __shared__ __align__(16) bf16_t s_x[M * LDA];
    __shared__ int s_idx[M * DMAXX];
    __shared__ int s_deg[M];

    for (int i = tid; i < M * DMAXX; i += NT) {
        int m = i >> 4;
        int node = node0 + m; if (node >= NN) node = NN - 1;
        int v = nbr_idx[node * DMAXX + (i & 15)];
        if (v < 0) v = 0; if (v >= NN) v = NN - 1;
        s_idx[i] = v;
    }
    for (int i = tid; i < M; i += NT) {
        int node = node0 + i; if (node >= NN) node = NN - 1;
        s_deg[i] = deg[node];
    }
    for (int i = tid; i < M * LDA; i += NT) s_h[i] = (bf16_t)0.0f;
    stage_tile<F, LDA, NT, XF32>(s_x, xself_v, node0, tid);   // own rows, for epilogue
    __syncthreads();

    int dg[RT][4];
    #pragma unroll
    for (int rt = 0; rt < RT; ++rt)
        #pragma unroll
        for (int r = 0; r < 4; ++r)
            dg[rt][r] = s_deg[rt * 16 + q * 4 + r];

    f32x4 c_[RT][CT];
    #pragma unroll
    for (int rt = 0; rt < RT; ++rt)
        #pragma unroll
        for (int ct = 0; ct < CT; ++ct)
            #pragma unroll
            for (int r = 0; r < 4; ++r) c_[rt][ct][r] = 0.0f;

    float hn[RT][CT][4];

    #pragma unroll 1
    for (int t = 0; t < DMAXX; ++t) {
        #pragma unroll
        for (int ct = 0; ct < CT; ++ct) {
            // gather gate-init (xg includes x@Wih^T + both biases), 8B/elem,
            // NONTEMPORAL: streaming gathers must not evict L2-resident Whh
            u16x4 u[RT][4];
            #pragma unroll
            for (int rt = 0; rt < RT; ++rt)
                #pragma unroll
                for (int r = 0; r < 4; ++r) {
                    int row = s_idx[(rt * 16 + q * 4 + r) * DMAXX + t];
                    u[rt][r] = __builtin_nontemporal_load(
                        reinterpret_cast<const u16x4*>(
                            xg + (size_t)row * G4 + (size_t)(wave * CPW + ct * 16 + m16) * 4));
                }
            f32x4 acc[RT][4];
            #pragma unroll
            for (int rt = 0; rt < RT; ++rt)
                #pragma unroll
                for (int g = 0; g < 4; ++g)
                    #pragma unroll
                    for (int r = 0; r < 4; ++r) acc[rt][g][r] = 0.0f;
            #pragma unroll
            for (int kk = 0; kk < KK; ++kk) {
                const int ko = kk * 32 + q * 8;
                bf16x8 ah[RT];
                #pragma unroll
                for (int rt = 0; rt < RT; ++rt)
                    ah[rt] = *reinterpret_cast<const bf16x8*>(&s_h[(rt * 16 + m16) * LDA + ko]);
                #pragma unroll
                for (int g = 0; g < 4; ++g) {
                    bf16x8 bh = *reinterpret_cast<const bf16x8*>(
                        Whh + (size_t)(g * F + wave * CPW + ct * 16 + m16) * F + ko);
                    #pragma unroll
                    for (int rt = 0; rt < RT; ++rt)
                        acc[rt][g] = __builtin_amdgcn_mfma_f32_16x16x32_bf16(ah[rt], bh, acc[rt][g], 0, 0, 0);
                }
            }
            // pointwise LSTM update for this col-tile
            #pragma unroll
            for (int rt = 0; rt < RT; ++rt)
                #pragma unroll
                for (int r = 0; r < 4; ++r) {
                    float iv = fsig (acc[rt][0][r] + bf2f(u[rt][r].x));
                    float fv = fsig (acc[rt][1][r] + bf2f(u[rt][r].y));
                    float gv = ftanh(acc[rt][2][r] + bf2f(u[rt][r].z));
                    float ov = fsig (acc[rt][3][r] + bf2f(u[rt][r].w));
                    float cn = fv * c_[rt][ct][r] + iv * gv;
                    float hv = ov * ftanh(cn);
                    if (t < dg[rt][r]) c_[rt][ct][r] = cn;  // t >= deg: state untouched
                    hn[rt][ct][r] = hv;
                }
        }
        __syncthreads();   // all s_h reads for step t complete
        #pragma unroll
        for (int rt = 0; rt < RT; ++rt)
            #pragma unroll
            for (int ct = 0; ct < CT; ++ct)
                #pragma unroll
                for (int r = 0; r < 4; ++r)
                    if (t < dg[rt][r])
                        s_h[(rt * 16 + q * 4 + r) * LDA + wave * CPW + ct * 16 + m16] =
                            (bf16_t)hn[rt][ct][r];
        __syncthreads();
    }

    // epilogue: out = x_self @ Wself^T + h_fin @ Wneigh^T + bout (+relu)
    constexpr int NCT = OUTF / 16;
    constexpr int TILES = NCT * RT;
    constexpr int TPW = TILES / NW;
    static_assert(TILES % NW == 0, "");
    #pragma unroll
    for (int tt = 0; tt < TPW; ++tt) {
        int tile = wave * TPW + tt;
        int ot = tile % NCT, rt = tile / NCT;
        f32x4 o;
        o[0] = 0.f; o[1] = 0.f; o[2] = 0.f; o[3] = 0.f;
        #pragma unroll
        for (int kk = 0; kk < KK; ++kk) {
            const int ko = kk * 32 + q * 8;
            bf16x8 axs = *reinterpret_cast<const bf16x8*>(&s_x[(rt * 16 + m16) * LDA + ko]);
            bf16x8 am  = *reinterpret_cast<const bf16x8*>(&s_h[(rt * 16 + m16) * LDA + ko]);
            bf16x8 bs = *reinterpret_cast<const bf16x8*>(Wself  + (size_t)(ot * 16 + m16) * F + ko);
            bf16x8 bn = *reinterpret_cast<const bf16x8*>(Wneigh + (size_t)(ot * 16 + m16) * F + ko);
            o = __builtin_amdgcn_mfma_f32_16x16x32_bf16(axs, bs, o, 0, 0, 0);
            o = __builtin_amdgcn_mfma_f32_16x16x32_bf16(am,  bn, o, 0, 0, 0);
        }
        int ocol = ot * 16 + m16;
        float bias = bout[ocol];
        #pragma unroll
        for (int r = 0; r < 4; ++r) {
            int node = node0 + rt * 16 + q * 4 + r;
            if (node < NN) {
                float v = o[r] + bias;
                if (RELU) v = fmaxf(v, 0.0f);
                outp[(size_t)node * OUTF + ocol] = (OutT)v;
            }
        }
    }
}

extern "C" void kernel_launch(void* const* d_in, const int* in_sizes, int n_in,
                              void* d_out, int out_size, void* d_ws, size_t ws_size,
                              hipStream_t stream)
{
    const float* feat    = (const float*)d_in[0];
    const int*   nbr     = (const int*)d_in[1];
    const int*   degp    = (const int*)d_in[2];
    const float* Wih1    = (const float*)d_in[3];
    const float* Whh1    = (const float*)d_in[4];
    const float* bih1    = (const float*)d_in[5];
    const float* bhh1    = (const float*)d_in[6];
    const float* Wself1  = (const float*)d_in[7];
    const float* Wneigh1 = (const float*)d_in[8];
    const float* b1      = (const float*)d_in[9];
    const float* Wih2    = (const float*)d_in[10];
    const float* Whh2    = (const float*)d_in[11];
    const float* bih2    = (const float*)d_in[12];
    const float* bhh2    = (const float*)d_in[13];
    const float* Wself2  = (const float*)d_in[14];
    const float* Wneigh2 = (const float*)d_in[15];
    const float* b2      = (const float*)d_in[16];

    bf16_t *hglob, *wglob, *xg1, *xg2;
    hipGetSymbolAddress((void**)&hglob, HIP_SYMBOL(g_hbuf));
    hipGetSymbolAddress((void**)&wglob, HIP_SYMBOL(g_wbuf));
    hipGetSymbolAddress((void**)&xg1,   HIP_SYMBOL(g_xg1));
    hipGetSymbolAddress((void**)&xg2,   HIP_SYMBOL(g_xg2));

    cvt_weights<<<W_TOTAL / 4 / 256, 256, 0, stream>>>(
        Wih1, Whh1, Wself1, Wneigh1, Wih2, Whh2, Wself2, Wneigh2);

    const int grid = (NN + 63) / 64;   // 469 WGs

    xg_gemm<128, 512, 8, true><<<grid, 512, 0, stream>>>(
        feat, wglob + OFF_WIH1, bih1, bhh1, xg1);

    sage_rec<128, 8, 256, true, true, bf16_t><<<grid, 512, 0, stream>>>(
        feat, xg1, nbr, degp, wglob + OFF_WHH1,
        wglob + OFF_WSELF1, wglob + OFF_WNEIGH1, b1, hglob);

    xg_gemm<256, 1024, 8, false><<<grid, 512, 0, stream>>>(
        hglob, wglob + OFF_WIH2, bih2, bhh2, xg2);

    sage_rec<256, 8, 64, false, false, float><<<grid, 512, 0, stream>>>(
        hglob, xg2, nbr, degp, wglob + OFF_WHH2,
        wglob + OFF_WSELF2, wglob + OFF_WNEIGH2, b2, (float*)d_out);
}

// Round 6
// 1895.530 us; speedup vs baseline: 1.7214x; 1.2312x over previous
//
#include <hip/hip_runtime.h>
#include <hip/hip_bf16.h>
#include <stdint.h>

// SAGE (GraphSAGE, LSTM aggregator). f32 I/O, bf16-granularity comparison ->
// bf16 MFMA internally. N=30000, DMAX=16, dims 128 -> 256 -> 64.
// R5 -> R6 (R5: neutral; VGPR stuck at 128, WRITE_SIZE still 1.65 GB ->
// spills persisted; launch_bounds cap didn't help because arch live set
// (~130) + 64 AGPRs exceeds the 128-arch split):
//   1. DOUBLE-BUFFERED s_h: read buf[t&1], write buf[(t+1)&1]. Kills the
//      deferred-writeback live range (store issues right after pointwise),
//      one barrier per step instead of two. Masked carry via hcur registers.
//   2. s_x eliminated: self-rows staged into the retired buffer post-loop
//      (final h is in buf[0]; x goes to buf[1]).
//   3. Gathers stay early (latency hidden over MFMA loop).
// Verified layouts (learn_hip m89/m91): A[m=lane&15][k=q*8+j],
// D[row=q*4+r][col=lane&15]; W[4F,F] row-major == gemm-BT B-frag layout.

#define NN 30000
#define DMAXX 16

typedef __bf16 bf16_t;
typedef __bf16 bf16x8 __attribute__((ext_vector_type(8)));
typedef float f32x4 __attribute__((ext_vector_type(4)));
typedef unsigned short u16x4 __attribute__((ext_vector_type(4)));

// persistent scratch (fully rewritten every call; no cross-call state reuse)
__device__ __align__(16) bf16_t g_hbuf[(size_t)NN * 256];    // layer-1 output h1
__device__ __align__(16) bf16_t g_xg1[(size_t)NN * 512];     // feat@Wih1^T + biases
__device__ __align__(16) bf16_t g_xg2[(size_t)NN * 1024];    // h1@Wih2^T + biases
__device__ __align__(16) bf16_t g_wbuf[753664];              // bf16 weight copies

#define OFF_WIH1 0
#define OFF_WHH1 65536
#define OFF_WSELF1 131072
#define OFF_WNEIGH1 163840
#define OFF_WIH2 196608
#define OFF_WHH2 458752
#define OFF_WSELF2 720896
#define OFF_WNEIGH2 737280
#define W_TOTAL 753664

__global__ __launch_bounds__(256)
void cvt_weights(const float* __restrict__ s0, const float* __restrict__ s1,
                 const float* __restrict__ s2, const float* __restrict__ s3,
                 const float* __restrict__ s4, const float* __restrict__ s5,
                 const float* __restrict__ s6, const float* __restrict__ s7)
{
    int i = (blockIdx.x * 256 + threadIdx.x) * 4;
    if (i >= W_TOTAL) return;
    const float* src; int off;
    if      (i < OFF_WHH1)   { src = s0; off = OFF_WIH1; }
    else if (i < OFF_WSELF1) { src = s1; off = OFF_WHH1; }
    else if (i < OFF_WNEIGH1){ src = s2; off = OFF_WSELF1; }
    else if (i < OFF_WIH2)   { src = s3; off = OFF_WNEIGH1; }
    else if (i < OFF_WHH2)   { src = s4; off = OFF_WIH2; }
    else if (i < OFF_WSELF2) { src = s5; off = OFF_WHH2; }
    else if (i < OFF_WNEIGH2){ src = s6; off = OFF_WSELF2; }
    else                     { src = s7; off = OFF_WNEIGH2; }
    float4 v = *reinterpret_cast<const float4*>(src + (i - off));
    bf16_t o[4] __attribute__((aligned(8)));
    o[0] = (bf16_t)v.x; o[1] = (bf16_t)v.y; o[2] = (bf16_t)v.z; o[3] = (bf16_t)v.w;
    *reinterpret_cast<uint2*>(&g_wbuf[i]) = *reinterpret_cast<const uint2*>(o);
}

__device__ __forceinline__ float fsig(float x) { return 1.0f / (1.0f + __expf(-x)); }
__device__ __forceinline__ float ftanh(float x) { return 1.0f - 2.0f / (__expf(2.0f * x) + 1.0f); }
__device__ __forceinline__ float bf2f(unsigned short s) {
    union { unsigned u; float f; } v; v.u = ((unsigned)s) << 16; return v.f;
}

// stage a 64-row x-tile (global, row-clamped) into LDS as bf16
template<int F, int LDA, int NT, bool XF32>
__device__ __forceinline__ void stage_tile(bf16_t* dst, const void* src, int row0, int tid)
{
    constexpr int UN = F / 8;          // 16B(bf16) units per row
    for (int e = tid; e < 64 * UN; e += NT) {
        int m = e / UN, sub = e - m * UN;
        int row = row0 + m; if (row >= NN) row = NN - 1;
        if constexpr (XF32) {
            const float* p = (const float*)src + (size_t)row * F + sub * 8;
            float4 f0 = reinterpret_cast<const float4*>(p)[0];
            float4 f1 = reinterpret_cast<const float4*>(p)[1];
            bf16_t t[8] __attribute__((aligned(16)));
            t[0]=(bf16_t)f0.x; t[1]=(bf16_t)f0.y; t[2]=(bf16_t)f0.z; t[3]=(bf16_t)f0.w;
            t[4]=(bf16_t)f1.x; t[5]=(bf16_t)f1.y; t[6]=(bf16_t)f1.z; t[7]=(bf16_t)f1.w;
            *reinterpret_cast<uint4*>(&dst[m * LDA + sub * 8]) = *reinterpret_cast<const uint4*>(t);
        } else {
            const bf16_t* p = (const bf16_t*)src + (size_t)row * F + sub * 8;
            *reinterpret_cast<uint4*>(&dst[m * LDA + sub * 8]) = *reinterpret_cast<const uint4*>(p);
        }
    }
}

// xg[N, 4F] (gate-interleaved [c][g]) = x[N,F] @ W[4F,F]^T + b0 + b1
template<int F, int G, int NW, bool XF32>
__global__ __launch_bounds__(NW * 64, 2)
void xg_gemm(const void* __restrict__ xsrc_v, const bf16_t* __restrict__ W,
             const float* __restrict__ b0, const float* __restrict__ b1v,
             bf16_t* __restrict__ xg)
{
    constexpr int LDA = F + 8, KK = F / 32, NT = NW * 64;
    constexpr int CPW = G / NW;        // linear out-cols per wave
    constexpr int CT = CPW / 16;
    static_assert(CPW % 16 == 0 && F % 16 == 0, "");
    const int tid = threadIdx.x, wave = tid >> 6, lane = tid & 63;
    const int q = lane >> 4, m16 = lane & 15;
    const int row0 = blockIdx.x * 64;

    __shared__ __align__(16) bf16_t s_x[64 * LDA];
    stage_tile<F, LDA, NT, XF32>(s_x, xsrc_v, row0, tid);
    __syncthreads();

    #pragma unroll
    for (int ct = 0; ct < CT; ++ct) {
        const int lc0 = wave * CPW + ct * 16;   // linear col block (within one gate)
        const int g = lc0 / F, c0 = lc0 - g * F;
        const float bias = b0[lc0 + m16] + b1v[lc0 + m16];
        f32x4 acc[4];
        #pragma unroll
        for (int rt = 0; rt < 4; ++rt)
            #pragma unroll
            for (int r = 0; r < 4; ++r) acc[rt][r] = bias;
        #pragma unroll
        for (int kk = 0; kk < KK; ++kk) {
            const int ko = kk * 32 + q * 8;
            bf16x8 b = *reinterpret_cast<const bf16x8*>(W + (size_t)(lc0 + m16) * F + ko);
            #pragma unroll
            for (int rt = 0; rt < 4; ++rt) {
                bf16x8 a = *reinterpret_cast<const bf16x8*>(&s_x[(rt * 16 + m16) * LDA + ko]);
                acc[rt] = __builtin_amdgcn_mfma_f32_16x16x32_bf16(a, b, acc[rt], 0, 0, 0);
            }
        }
        #pragma unroll
        for (int rt = 0; rt < 4; ++rt)
            #pragma unroll
            for (int r = 0; r < 4; ++r) {
                int row = row0 + rt * 16 + q * 4 + r;
                if (row < NN) {
                    bf16_t o = (bf16_t)acc[rt][r];
                    __builtin_nontemporal_store((unsigned short&)o,
                        (unsigned short*)(xg + (size_t)row * G + (size_t)(c0 + m16) * 4 + g));
                }
            }
    }
}

// LSTM recurrence over gathered neighbors + fused fc epilogue.
// gates = gather(xg) + h @ Whh^T ; out = x_self@Wself^T + h_fin@Wneigh^T + b
template<int F, int NW, int OUTF, bool RELU, bool XF32, typename OutT>
__global__ __launch_bounds__(NW * 64, 2)
void sage_rec(const void* __restrict__ xself_v,
              const bf16_t* __restrict__ xg,
              const int* __restrict__ nbr_idx, const int* __restrict__ deg,
              const bf16_t* __restrict__ Whh,
              const bf16_t* __restrict__ Wself, const bf16_t* __restrict__ Wneigh,
              const float* __restrict__ bout, OutT* __restrict__ outp)
{
    constexpr int M = 64, RT = 4, LDA = F + 8, KK = F / 32, NT = NW * 64;
    constexpr int CPW = F / NW, CT = CPW / 16, G4 = 4 * F;
    static_assert(CPW % 16 == 0, "");
    static_assert((DMAXX & 1) == 0, "final h must land in buf[0]");
    const int tid = threadIdx.x, wave = tid >> 6, lane = tid & 63;
    const int q = lane >> 4, m16 = lane & 15;
    const int node0 = blockIdx.x * M;

    __shared__ __align__(16) bf16_t s_h[2][M * LDA];   // double-buffered h
    __shared__ int s_idx[M * DMAXX];
    __shared__ int s_deg[M];

    for (int i = tid; i < M * DMAXX; i += NT) {
        int m = i >> 4;
        int node = node0 + m; if (node >= NN) node = NN - 1;
        int v = nbr_idx[node * DMAXX + (i & 15)];
        if (v < 0) v = 0; if (v >= NN) v = NN - 1;
        s_idx[i] = v;
    }
    for (int i = tid; i < M; i += NT) {
        int node = node0 + i; if (node >= NN) node = NN - 1;
        s_deg[i] = deg[node];
    }
    for (int i = tid; i < M * LDA; i += NT) s_h[0][i] = (bf16_t)0.0f;
    __syncthreads();

    int dg[RT][4];
    #pragma unroll
    for (int rt = 0; rt < RT; ++rt)
        #pragma unroll
        for (int r = 0; r < 4; ++r)
            dg[rt][r] = s_deg[rt * 16 + q * 4 + r];

    f32x4 c_[RT][CT];
    float hcur[RT][CT][4];   // h value this thread owns (D-layout), for masked carry
    #pragma unroll
    for (int rt = 0; rt < RT; ++rt)
        #pragma unroll
        for (int ct = 0; ct < CT; ++ct)
            #pragma unroll
            for (int r = 0; r < 4; ++r) { c_[rt][ct][r] = 0.0f; hcur[rt][ct][r] = 0.0f; }

    #pragma unroll 1
    for (int t = 0; t < DMAXX; ++t) {
        const bf16_t* cur = s_h[t & 1];
        bf16_t* nxt = s_h[(t + 1) & 1];
        #pragma unroll
        for (int ct = 0; ct < CT; ++ct) {
            // gather gate-init (xg = x@Wih^T + biases), 8B/elem, nontemporal
            u16x4 u[RT][4];
            #pragma unroll
            for (int rt = 0; rt < RT; ++rt)
                #pragma unroll
                for (int r = 0; r < 4; ++r) {
                    int row = s_idx[(rt * 16 + q * 4 + r) * DMAXX + t];
                    u[rt][r] = __builtin_nontemporal_load(
                        reinterpret_cast<const u16x4*>(
                            xg + (size_t)row * G4 + (size_t)(wave * CPW + ct * 16 + m16) * 4));
                }
            f32x4 acc[RT][4];
            #pragma unroll
            for (int rt = 0; rt < RT; ++rt)
                #pragma unroll
                for (int g = 0; g < 4; ++g)
                    #pragma unroll
                    for (int r = 0; r < 4; ++r) acc[rt][g][r] = 0.0f;
            #pragma unroll
            for (int kk = 0; kk < KK; ++kk) {
                const int ko = kk * 32 + q * 8;
                bf16x8 ah[RT];
                #pragma unroll
                for (int rt = 0; rt < RT; ++rt)
                    ah[rt] = *reinterpret_cast<const bf16x8*>(&cur[(rt * 16 + m16) * LDA + ko]);
                #pragma unroll
                for (int g = 0; g < 4; ++g) {
                    bf16x8 bh = *reinterpret_cast<const bf16x8*>(
                        Whh + (size_t)(g * F + wave * CPW + ct * 16 + m16) * F + ko);
                    #pragma unroll
                    for (int rt = 0; rt < RT; ++rt)
                        acc[rt][g] = __builtin_amdgcn_mfma_f32_16x16x32_bf16(ah[rt], bh, acc[rt][g], 0, 0, 0);
                }
            }
            // pointwise LSTM update + immediate store to the other buffer
            #pragma unroll
            for (int rt = 0; rt < RT; ++rt)
                #pragma unroll
                for (int r = 0; r < 4; ++r) {
                    float iv = fsig (acc[rt][0][r] + bf2f(u[rt][r].x));
                    float fv = fsig (acc[rt][1][r] + bf2f(u[rt][r].y));
                    float gv = ftanh(acc[rt][2][r] + bf2f(u[rt][r].z));
                    float ov = fsig (acc[rt][3][r] + bf2f(u[rt][r].w));
                    float cn = fv * c_[rt][ct][r] + iv * gv;
                    float hv = ov * ftanh(cn);
                    bool take = (t < dg[rt][r]);           // t >= deg: state untouched
                    if (take) { c_[rt][ct][r] = cn; hcur[rt][ct][r] = hv; }
                    nxt[(rt * 16 + q * 4 + r) * LDA + wave * CPW + ct * 16 + m16] =
                        (bf16_t)hcur[rt][ct][r];
                }
        }
        __syncthreads();   // nxt fully written; cur fully consumed
    }

    // final h is in s_h[0]; stage self-rows into retired s_h[1] for epilogue
    stage_tile<F, LDA, NT, XF32>(s_h[1], xself_v, node0, tid);
    __syncthreads();

    // epilogue: out = x_self @ Wself^T + h_fin @ Wneigh^T + bout (+relu)
    constexpr int NCT = OUTF / 16;
    constexpr int TILES = NCT * RT;
    constexpr int TPW = TILES / NW;
    static_assert(TILES % NW == 0, "");
    #pragma unroll
    for (int tt = 0; tt < TPW; ++tt) {
        int tile = wave * TPW + tt;
        int ot = tile % NCT, rt = tile / NCT;
        f32x4 o;
        o[0] = 0.f; o[1] = 0.f; o[2] = 0.f; o[3] = 0.f;
        #pragma unroll
        for (int kk = 0; kk < KK; ++kk) {
            const int ko = kk * 32 + q * 8;
            bf16x8 axs = *reinterpret_cast<const bf16x8*>(&s_h[1][(rt * 16 + m16) * LDA + ko]);
            bf16x8 am  = *reinterpret_cast<const bf16x8*>(&s_h[0][(rt * 16 + m16) * LDA + ko]);
            bf16x8 bs = *reinterpret_cast<const bf16x8*>(Wself  + (size_t)(ot * 16 + m16) * F + ko);
            bf16x8 bn = *reinterpret_cast<const bf16x8*>(Wneigh + (size_t)(ot * 16 + m16) * F + ko);
            o = __builtin_amdgcn_mfma_f32_16x16x32_bf16(axs, bs, o, 0, 0, 0);
            o = __builtin_amdgcn_mfma_f32_16x16x32_bf16(am,  bn, o, 0, 0, 0);
        }
        int ocol = ot * 16 + m16;
        float bias = bout[ocol];
        #pragma unroll
        for (int r = 0; r < 4; ++r) {
            int node = node0 + rt * 16 + q * 4 + r;
            if (node < NN) {
                float v = o[r] + bias;
                if (RELU) v = fmaxf(v, 0.0f);
                outp[(size_t)node * OUTF + ocol] = (OutT)v;
            }
        }
    }
}

extern "C" void kernel_launch(void* const* d_in, const int* in_sizes, int n_in,
                              void* d_out, int out_size, void* d_ws, size_t ws_size,
                              hipStream_t stream)
{
    const float* feat    = (const float*)d_in[0];
    const int*   nbr     = (const int*)d_in[1];
    const int*   degp    = (const int*)d_in[2];
    const float* Wih1    = (const float*)d_in[3];
    const float* Whh1    = (const float*)d_in[4];
    const float* bih1    = (const float*)d_in[5];
    const float* bhh1    = (const float*)d_in[6];
    const float* Wself1  = (const float*)d_in[7];
    const float* Wneigh1 = (const float*)d_in[8];
    const float* b1      = (const float*)d_in[9];
    const float* Wih2    = (const float*)d_in[10];
    const float* Whh2    = (const float*)d_in[11];
    const float* bih2    = (const float*)d_in[12];
    const float* bhh2    = (const float*)d_in[13];
    const float* Wself2  = (const float*)d_in[14];
    const float* Wneigh2 = (const float*)d_in[15];
    const float* b2      = (const float*)d_in[16];

    bf16_t *hglob, *wglob, *xg1, *xg2;
    hipGetSymbolAddress((void**)&hglob, HIP_SYMBOL(g_hbuf));
    hipGetSymbolAddress((void**)&wglob, HIP_SYMBOL(g_wbuf));
    hipGetSymbolAddress((void**)&xg1,   HIP_SYMBOL(g_xg1));
    hipGetSymbolAddress((void**)&xg2,   HIP_SYMBOL(g_xg2));

    cvt_weights<<<W_TOTAL / 4 / 256, 256, 0, stream>>>(
        Wih1, Whh1, Wself1, Wneigh1, Wih2, Whh2, Wself2, Wneigh2);

    const int grid = (NN + 63) / 64;   // 469 WGs

    xg_gemm<128, 512, 8, true><<<grid, 512, 0, stream>>>(
        feat, wglob + OFF_WIH1, bih1, bhh1, xg1);

    sage_rec<128, 8, 256, true, true, bf16_t><<<grid, 512, 0, stream>>>(
        feat, xg1, nbr, degp, wglob + OFF_WHH1,
        wglob + OFF_WSELF1, wglob + OFF_WNEIGH1, b1, hglob);

    xg_gemm<256, 1024, 8, false><<<grid, 512, 0, stream>>>(
        hglob, wglob + OFF_WIH2, bih2, bhh2, xg2);

    sage_rec<256, 8, 64, false, false, float><<<grid, 512, 0, stream>>>(
        hglob, xg2, nbr, degp, wglob + OFF_WHH2,
        wglob + OFF_WSELF2, wglob + OFF_WNEIGH2, b2, (float*)d_out);
}

// Round 7
// 1644.255 us; speedup vs baseline: 1.9845x; 1.1528x over previous
//
#include <hip/hip_runtime.h>
#include <hip/hip_bf16.h>
#include <stdint.h>

// SAGE (GraphSAGE, LSTM aggregator). f32 I/O, bf16-granularity comparison ->
// bf16 MFMA internally. N=30000, DMAX=16, dims 128 -> 256 -> 64.
// R6 -> R7 (R6: 1896us; rec2 1270us FETCH 2.54GB ~= whole dispatch at 2.4TB/s
// -> HBM-fetch bound; ~1GB of it self-inflicted by nontemporal xg stores
// (bypass L3 -> every gather re-fetches HBM); plus ~460MB residual spill):
//   1. Remove ALL nontemporal hints. xg tables (31/61 MB) << 256 MB L3 ->
//      gathers become L3 hits after cold fill.
//   2. Delete hcur[32] regs: frozen threads (t >= deg+1) SKIP the store
//      (nxt already holds h^(t-1) = frozen value, buffers alternate);
//      boundary t == deg copies cur[pos] -> nxt[pos] (raw 2B LDS copy,
//      rare + divergent). Arch live ~100 < 128 -> zero spill.
// Verified layouts (learn_hip m89/m91): A[m=lane&15][k=q*8+j],
// D[row=q*4+r][col=lane&15]; W[4F,F] row-major == gemm-BT B-frag layout.

#define NN 30000
#define DMAXX 16

typedef __bf16 bf16_t;
typedef __bf16 bf16x8 __attribute__((ext_vector_type(8)));
typedef float f32x4 __attribute__((ext_vector_type(4)));
typedef unsigned short u16x4 __attribute__((ext_vector_type(4)));

// persistent scratch (fully rewritten every call; no cross-call state reuse)
__device__ __align__(16) bf16_t g_hbuf[(size_t)NN * 256];    // layer-1 output h1
__device__ __align__(16) bf16_t g_xg1[(size_t)NN * 512];     // feat@Wih1^T + biases
__device__ __align__(16) bf16_t g_xg2[(size_t)NN * 1024];    // h1@Wih2^T + biases
__device__ __align__(16) bf16_t g_wbuf[753664];              // bf16 weight copies

#define OFF_WIH1 0
#define OFF_WHH1 65536
#define OFF_WSELF1 131072
#define OFF_WNEIGH1 163840
#define OFF_WIH2 196608
#define OFF_WHH2 458752
#define OFF_WSELF2 720896
#define OFF_WNEIGH2 737280
#define W_TOTAL 753664

__global__ __launch_bounds__(256)
void cvt_weights(const float* __restrict__ s0, const float* __restrict__ s1,
                 const float* __restrict__ s2, const float* __restrict__ s3,
                 const float* __restrict__ s4, const float* __restrict__ s5,
                 const float* __restrict__ s6, const float* __restrict__ s7)
{
    int i = (blockIdx.x * 256 + threadIdx.x) * 4;
    if (i >= W_TOTAL) return;
    const float* src; int off;
    if      (i < OFF_WHH1)   { src = s0; off = OFF_WIH1; }
    else if (i < OFF_WSELF1) { src = s1; off = OFF_WHH1; }
    else if (i < OFF_WNEIGH1){ src = s2; off = OFF_WSELF1; }
    else if (i < OFF_WIH2)   { src = s3; off = OFF_WNEIGH1; }
    else if (i < OFF_WHH2)   { src = s4; off = OFF_WIH2; }
    else if (i < OFF_WSELF2) { src = s5; off = OFF_WHH2; }
    else if (i < OFF_WNEIGH2){ src = s6; off = OFF_WSELF2; }
    else                     { src = s7; off = OFF_WNEIGH2; }
    float4 v = *reinterpret_cast<const float4*>(src + (i - off));
    bf16_t o[4] __attribute__((aligned(8)));
    o[0] = (bf16_t)v.x; o[1] = (bf16_t)v.y; o[2] = (bf16_t)v.z; o[3] = (bf16_t)v.w;
    *reinterpret_cast<uint2*>(&g_wbuf[i]) = *reinterpret_cast<const uint2*>(o);
}

__device__ __forceinline__ float fsig(float x) { return 1.0f / (1.0f + __expf(-x)); }
__device__ __forceinline__ float ftanh(float x) { return 1.0f - 2.0f / (__expf(2.0f * x) + 1.0f); }
__device__ __forceinline__ float bf2f(unsigned short s) {
    union { unsigned u; float f; } v; v.u = ((unsigned)s) << 16; return v.f;
}

// stage a 64-row x-tile (global, row-clamped) into LDS as bf16
template<int F, int LDA, int NT, bool XF32>
__device__ __forceinline__ void stage_tile(bf16_t* dst, const void* src, int row0, int tid)
{
    constexpr int UN = F / 8;          // 16B(bf16) units per row
    for (int e = tid; e < 64 * UN; e += NT) {
        int m = e / UN, sub = e - m * UN;
        int row = row0 + m; if (row >= NN) row = NN - 1;
        if constexpr (XF32) {
            const float* p = (const float*)src + (size_t)row * F + sub * 8;
            float4 f0 = reinterpret_cast<const float4*>(p)[0];
            float4 f1 = reinterpret_cast<const float4*>(p)[1];
            bf16_t t[8] __attribute__((aligned(16)));
            t[0]=(bf16_t)f0.x; t[1]=(bf16_t)f0.y; t[2]=(bf16_t)f0.z; t[3]=(bf16_t)f0.w;
            t[4]=(bf16_t)f1.x; t[5]=(bf16_t)f1.y; t[6]=(bf16_t)f1.z; t[7]=(bf16_t)f1.w;
            *reinterpret_cast<uint4*>(&dst[m * LDA + sub * 8]) = *reinterpret_cast<const uint4*>(t);
        } else {
            const bf16_t* p = (const bf16_t*)src + (size_t)row * F + sub * 8;
            *reinterpret_cast<uint4*>(&dst[m * LDA + sub * 8]) = *reinterpret_cast<const uint4*>(p);
        }
    }
}

// xg[N, 4F] (gate-interleaved [c][g]) = x[N,F] @ W[4F,F]^T + b0 + b1
template<int F, int G, int NW, bool XF32>
__global__ __launch_bounds__(NW * 64, 2)
void xg_gemm(const void* __restrict__ xsrc_v, const bf16_t* __restrict__ W,
             const float* __restrict__ b0, const float* __restrict__ b1v,
             bf16_t* __restrict__ xg)
{
    constexpr int LDA = F + 8, KK = F / 32, NT = NW * 64;
    constexpr int CPW = G / NW;        // linear out-cols per wave
    constexpr int CT = CPW / 16;
    static_assert(CPW % 16 == 0 && F % 16 == 0, "");
    const int tid = threadIdx.x, wave = tid >> 6, lane = tid & 63;
    const int q = lane >> 4, m16 = lane & 15;
    const int row0 = blockIdx.x * 64;

    __shared__ __align__(16) bf16_t s_x[64 * LDA];
    stage_tile<F, LDA, NT, XF32>(s_x, xsrc_v, row0, tid);
    __syncthreads();

    #pragma unroll
    for (int ct = 0; ct < CT; ++ct) {
        const int lc0 = wave * CPW + ct * 16;   // linear col block (within one gate)
        const int g = lc0 / F, c0 = lc0 - g * F;
        const float bias = b0[lc0 + m16] + b1v[lc0 + m16];
        f32x4 acc[4];
        #pragma unroll
        for (int rt = 0; rt < 4; ++rt)
            #pragma unroll
            for (int r = 0; r < 4; ++r) acc[rt][r] = bias;
        #pragma unroll
        for (int kk = 0; kk < KK; ++kk) {
            const int ko = kk * 32 + q * 8;
            bf16x8 b = *reinterpret_cast<const bf16x8*>(W + (size_t)(lc0 + m16) * F + ko);
            #pragma unroll
            for (int rt = 0; rt < 4; ++rt) {
                bf16x8 a = *reinterpret_cast<const bf16x8*>(&s_x[(rt * 16 + m16) * LDA + ko]);
                acc[rt] = __builtin_amdgcn_mfma_f32_16x16x32_bf16(a, b, acc[rt], 0, 0, 0);
            }
        }
        #pragma unroll
        for (int rt = 0; rt < 4; ++rt)
            #pragma unroll
            for (int r = 0; r < 4; ++r) {
                int row = row0 + rt * 16 + q * 4 + r;
                if (row < NN)
                    xg[(size_t)row * G + (size_t)(c0 + m16) * 4 + g] = (bf16_t)acc[rt][r];
            }
    }
}

// LSTM recurrence over gathered neighbors + fused fc epilogue.
// gates = gather(xg) + h @ Whh^T ; out = x_self@Wself^T + h_fin@Wneigh^T + b
template<int F, int NW, int OUTF, bool RELU, bool XF32, typename OutT>
__global__ __launch_bounds__(NW * 64, 2)
void sage_rec(const void* __restrict__ xself_v,
              const bf16_t* __restrict__ xg,
              const int* __restrict__ nbr_idx, const int* __restrict__ deg,
              const bf16_t* __restrict__ Whh,
              const bf16_t* __restrict__ Wself, const bf16_t* __restrict__ Wneigh,
              const float* __restrict__ bout, OutT* __restrict__ outp)
{
    constexpr int M = 64, RT = 4, LDA = F + 8, KK = F / 32, NT = NW * 64;
    constexpr int CPW = F / NW, CT = CPW / 16, G4 = 4 * F;
    static_assert(CPW % 16 == 0, "");
    static_assert((DMAXX & 1) == 0, "final h must land in buf[0]");
    const int tid = threadIdx.x, wave = tid >> 6, lane = tid & 63;
    const int q = lane >> 4, m16 = lane & 15;
    const int node0 = blockIdx.x * M;

    __shared__ __align__(16) bf16_t s_h[2][M * LDA];   // double-buffered h
    __shared__ int s_idx[M * DMAXX];
    __shared__ int s_deg[M];

    for (int i = tid; i < M * DMAXX; i += NT) {
        int m = i >> 4;
        int node = node0 + m; if (node >= NN) node = NN - 1;
        int v = nbr_idx[node * DMAXX + (i & 15)];
        if (v < 0) v = 0; if (v >= NN) v = NN - 1;
        s_idx[i] = v;
    }
    for (int i = tid; i < M; i += NT) {
        int node = node0 + i; if (node >= NN) node = NN - 1;
        s_deg[i] = deg[node];
    }
    for (int i = tid; i < M * LDA; i += NT) s_h[0][i] = (bf16_t)0.0f;
    __syncthreads();

    int dg[RT][4];
    #pragma unroll
    for (int rt = 0; rt < RT; ++rt)
        #pragma unroll
        for (int r = 0; r < 4; ++r)
            dg[rt][r] = s_deg[rt * 16 + q * 4 + r];

    f32x4 c_[RT][CT];
    #pragma unroll
    for (int rt = 0; rt < RT; ++rt)
        #pragma unroll
        for (int ct = 0; ct < CT; ++ct)
            #pragma unroll
            for (int r = 0; r < 4; ++r) c_[rt][ct][r] = 0.0f;

    #pragma unroll 1
    for (int t = 0; t < DMAXX; ++t) {
        const bf16_t* cur = s_h[t & 1];
        bf16_t* nxt = s_h[(t + 1) & 1];
        #pragma unroll
        for (int ct = 0; ct < CT; ++ct) {
            // gather gate-init (xg = x@Wih^T + biases), 8B/elem, cached (L3)
            u16x4 u[RT][4];
            #pragma unroll
            for (int rt = 0; rt < RT; ++rt)
                #pragma unroll
                for (int r = 0; r < 4; ++r) {
                    int row = s_idx[(rt * 16 + q * 4 + r) * DMAXX + t];
                    u[rt][r] = *reinterpret_cast<const u16x4*>(
                        xg + (size_t)row * G4 + (size_t)(wave * CPW + ct * 16 + m16) * 4);
                }
            f32x4 acc[RT][4];
            #pragma unroll
            for (int rt = 0; rt < RT; ++rt)
                #pragma unroll
                for (int g = 0; g < 4; ++g)
                    #pragma unroll
                    for (int r = 0; r < 4; ++r) acc[rt][g][r] = 0.0f;
            #pragma unroll
            for (int kk = 0; kk < KK; ++kk) {
                const int ko = kk * 32 + q * 8;
                bf16x8 ah[RT];
                #pragma unroll
                for (int rt = 0; rt < RT; ++rt)
                    ah[rt] = *reinterpret_cast<const bf16x8*>(&cur[(rt * 16 + m16) * LDA + ko]);
                #pragma unroll
                for (int g = 0; g < 4; ++g) {
                    bf16x8 bh = *reinterpret_cast<const bf16x8*>(
                        Whh + (size_t)(g * F + wave * CPW + ct * 16 + m16) * F + ko);
                    #pragma unroll
                    for (int rt = 0; rt < RT; ++rt)
                        acc[rt][g] = __builtin_amdgcn_mfma_f32_16x16x32_bf16(ah[rt], bh, acc[rt][g], 0, 0, 0);
                }
            }
            // pointwise LSTM update + masked store:
            //   t <  deg : write h_new (and update c)
            //   t == deg : copy frozen h from cur (this thread's t-1 write)
            //   t >  deg : skip -- nxt already holds the frozen value
            #pragma unroll
            for (int rt = 0; rt < RT; ++rt)
                #pragma unroll
                for (int r = 0; r < 4; ++r) {
                    float iv = fsig (acc[rt][0][r] + bf2f(u[rt][r].x));
                    float fv = fsig (acc[rt][1][r] + bf2f(u[rt][r].y));
                    float gv = ftanh(acc[rt][2][r] + bf2f(u[rt][r].z));
                    float ov = fsig (acc[rt][3][r] + bf2f(u[rt][r].w));
                    float cn = fv * c_[rt][ct][r] + iv * gv;
                    float hv = ov * ftanh(cn);
                    const int pos = (rt * 16 + q * 4 + r) * LDA + wave * CPW + ct * 16 + m16;
                    int d = dg[rt][r];
                    if (t < d) {
                        c_[rt][ct][r] = cn;
                        nxt[pos] = (bf16_t)hv;
                    } else if (t == d) {
                        reinterpret_cast<unsigned short*>(nxt)[pos] =
                            reinterpret_cast<const unsigned short*>(cur)[pos];
                    }
                }
        }
        __syncthreads();   // nxt fully written; cur fully consumed
    }

    // final h is in s_h[0]; stage self-rows into retired s_h[1] for epilogue
    stage_tile<F, LDA, NT, XF32>(s_h[1], xself_v, node0, tid);
    __syncthreads();

    // epilogue: out = x_self @ Wself^T + h_fin @ Wneigh^T + bout (+relu)
    constexpr int NCT = OUTF / 16;
    constexpr int TILES = NCT * RT;
    constexpr int TPW = TILES / NW;
    static_assert(TILES % NW == 0, "");
    #pragma unroll
    for (int tt = 0; tt < TPW; ++tt) {
        int tile = wave * TPW + tt;
        int ot = tile % NCT, rt = tile / NCT;
        f32x4 o;
        o[0] = 0.f; o[1] = 0.f; o[2] = 0.f; o[3] = 0.f;
        #pragma unroll
        for (int kk = 0; kk < KK; ++kk) {
            const int ko = kk * 32 + q * 8;
            bf16x8 axs = *reinterpret_cast<const bf16x8*>(&s_h[1][(rt * 16 + m16) * LDA + ko]);
            bf16x8 am  = *reinterpret_cast<const bf16x8*>(&s_h[0][(rt * 16 + m16) * LDA + ko]);
            bf16x8 bs = *reinterpret_cast<const bf16x8*>(Wself  + (size_t)(ot * 16 + m16) * F + ko);
            bf16x8 bn = *reinterpret_cast<const bf16x8*>(Wneigh + (size_t)(ot * 16 + m16) * F + ko);
            o = __builtin_amdgcn_mfma_f32_16x16x32_bf16(axs, bs, o, 0, 0, 0);
            o = __builtin_amdgcn_mfma_f32_16x16x32_bf16(am,  bn, o, 0, 0, 0);
        }
        int ocol = ot * 16 + m16;
        float bias = bout[ocol];
        #pragma unroll
        for (int r = 0; r < 4; ++r) {
            int node = node0 + rt * 16 + q * 4 + r;
            if (node < NN) {
                float v = o[r] + bias;
                if (RELU) v = fmaxf(v, 0.0f);
                outp[(size_t)node * OUTF + ocol] = (OutT)v;
            }
        }
    }
}

extern "C" void kernel_launch(void* const* d_in, const int* in_sizes, int n_in,
                              void* d_out, int out_size, void* d_ws, size_t ws_size,
                              hipStream_t stream)
{
    const float* feat    = (const float*)d_in[0];
    const int*   nbr     = (const int*)d_in[1];
    const int*   degp    = (const int*)d_in[2];
    const float* Wih1    = (const float*)d_in[3];
    const float* Whh1    = (const float*)d_in[4];
    const float* bih1    = (const float*)d_in[5];
    const float* bhh1    = (const float*)d_in[6];
    const float* Wself1  = (const float*)d_in[7];
    const float* Wneigh1 = (const float*)d_in[8];
    const float* b1      = (const float*)d_in[9];
    const float* Wih2    = (const float*)d_in[10];
    const float* Whh2    = (const float*)d_in[11];
    const float* bih2    = (const float*)d_in[12];
    const float* bhh2    = (const float*)d_in[13];
    const float* Wself2  = (const float*)d_in[14];
    const float* Wneigh2 = (const float*)d_in[15];
    const float* b2      = (const float*)d_in[16];

    bf16_t *hglob, *wglob, *xg1, *xg2;
    hipGetSymbolAddress((void**)&hglob, HIP_SYMBOL(g_hbuf));
    hipGetSymbolAddress((void**)&wglob, HIP_SYMBOL(g_wbuf));
    hipGetSymbolAddress((void**)&xg1,   HIP_SYMBOL(g_xg1));
    hipGetSymbolAddress((void**)&xg2,   HIP_SYMBOL(g_xg2));

    cvt_weights<<<W_TOTAL / 4 / 256, 256, 0, stream>>>(
        Wih1, Whh1, Wself1, Wneigh1, Wih2, Whh2, Wself2, Wneigh2);

    const int grid = (NN + 63) / 64;   // 469 WGs

    xg_gemm<128, 512, 8, true><<<grid, 512, 0, stream>>>(
        feat, wglob + OFF_WIH1, bih1, bhh1, xg1);

    sage_rec<128, 8, 256, true, true, bf16_t><<<grid, 512, 0, stream>>>(
        feat, xg1, nbr, degp, wglob + OFF_WHH1,
        wglob + OFF_WSELF1, wglob + OFF_WNEIGH1, b1, hglob);

    xg_gemm<256, 1024, 8, false><<<grid, 512, 0, stream>>>(
        hglob, wglob + OFF_WIH2, bih2, bhh2, xg2);

    sage_rec<256, 8, 64, false, false, float><<<grid, 512, 0, stream>>>(
        hglob, xg2, nbr, degp, wglob + OFF_WHH2,
        wglob + OFF_WSELF2, wglob + OFF_WNEIGH2, b2, (float*)d_out);
}